// Round 23
// baseline (124.397 us; speedup 1.0000x reference)
//
#include <hip/hip_runtime.h>
#include <hip/hip_bf16.h>

typedef __attribute__((ext_vector_type(4))) float f32x4;
typedef __attribute__((ext_vector_type(16))) float f32x16;
typedef __attribute__((ext_vector_type(8))) short s16x8;
typedef __attribute__((ext_vector_type(4))) float float4_t;
typedef __attribute__((ext_vector_type(2))) unsigned int u32x2;

union U8 { s16x8 v; unsigned u[4]; };

__device__ __forceinline__ ushort f2bf(float f) {
  union { float f; unsigned u; } v; v.f = f;
  unsigned r = v.u + 0x7fffu + ((v.u >> 16) & 1u);
  return (ushort)(r >> 16);
}

__device__ __forceinline__ void async_copy16(ushort* lds, const ushort* g) {
  __builtin_amdgcn_global_load_lds(
      (const __attribute__((address_space(1))) unsigned int*)g,
      (__attribute__((address_space(3))) unsigned int*)lds, 16, 0, 0);
}

__device__ __forceinline__ unsigned lds_addr(const void* p) {
  return (unsigned)(unsigned long long)(__attribute__((address_space(3))) const void*)p;
}

#define TRRD(dst, addr, off_lit) \
  asm volatile("ds_read_b64_tr_b16 %0, %1 offset:" #off_lit : "=v"(dst) : "v"(addr))

// ---------- merged f32 -> bf16 conversion into 32-col pre-swizzled panels ----------
// A: [tm 32][kt 32][128 rows][32 cols], chunk cg stored at cg ^ ((r>>1)&3).
// B: [tn 16][kt 32][192 rows][32 cols], same swizzle.
// Bank math: read bank = 16*(r&1) + 4*(l4 ^ ((r>>1)&3)) -> rows r,r+8 alias
// pairwise (2-way = free, m136); 4 chunk groups disjoint. (R21's r&3 gave 4-way.)
__global__ __launch_bounds__(256) void convert_kernel(
    const float* __restrict__ x, const float* __restrict__ Wq,
    const float* __restrict__ Wk, const float* __restrict__ Wv,
    ushort* __restrict__ xs, ushort* __restrict__ ws) {
  int b = blockIdx.x;
  if (b < 2048) {
    int c = b * 256 + threadIdx.x;
    int kc = c & 127;
    int m = c >> 7;
    const float4_t* s = (const float4_t*)&x[(size_t)m * 1024 + kc * 8];
    float4_t a0 = s[0], a1 = s[1];
    s16x8 v;
    v[0] = (short)f2bf(a0[0]); v[1] = (short)f2bf(a0[1]);
    v[2] = (short)f2bf(a0[2]); v[3] = (short)f2bf(a0[3]);
    v[4] = (short)f2bf(a1[0]); v[5] = (short)f2bf(a1[1]);
    v[6] = (short)f2bf(a1[2]); v[7] = (short)f2bf(a1[3]);
    int tm = m >> 7, r = m & 127;
    int kt = kc >> 2, cg = kc & 3;
    int cs = cg ^ ((r >> 1) & 3);
    *(s16x8*)&xs[((size_t)(tm * 32 + kt) * 128 + r) * 32 + cs * 8] = v;
  } else {
    int c = (b - 2048) * 256 + threadIdx.x;
    int kc = c & 127;
    int n = c >> 7;
    int p = n >> 10, nW = n & 1023;
    const float* __restrict__ W = (p == 0) ? Wq : (p == 1) ? Wk : Wv;
    const float4_t* s = (const float4_t*)&W[(size_t)nW * 1024 + kc * 8];
    float4_t a0 = s[0], a1 = s[1];
    s16x8 v;
    v[0] = (short)f2bf(a0[0]); v[1] = (short)f2bf(a0[1]);
    v[2] = (short)f2bf(a0[2]); v[3] = (short)f2bf(a0[3]);
    v[4] = (short)f2bf(a1[0]); v[5] = (short)f2bf(a1[1]);
    v[6] = (short)f2bf(a1[2]); v[7] = (short)f2bf(a1[3]);
    unsigned tn = (unsigned)n / 192u;
    unsigned r = (unsigned)n - tn * 192u;
    int kt = kc >> 2, cg = kc & 3;
    int cs = cg ^ (((int)r >> 1) & 3);
    *(s16x8*)&ws[((size_t)(tn * 32 + kt) * 192 + r) * 32 + cs * 8] = v;
  }
}

// -- fused QKV GEMM: 128x192 tile, BK=32, 4 waves x 64x96, dbuf, 4 blocks/CU --
// 40 KB LDS -> 4 co-resident blocks; corrected swizzle -> 2-way (free) LDS reads.
__global__ __launch_bounds__(256, 4) void qkv_gemm_kernel(
    const ushort* __restrict__ xs, const ushort* __restrict__ wsb,
    const float* __restrict__ bq, const float* __restrict__ bk,
    const float* __restrict__ bv, ushort* __restrict__ qkv) {
  __shared__ ushort lA[2][4096];    // [buf][128 rows * 32]
  __shared__ ushort lB[2][6144];    // [buf][192 rows * 32]
  const int t = threadIdx.x;
  const int lane = t & 63, w = t >> 6;
  const int wm = w >> 1, wn = w & 1;      // 2M x 2N waves, 64x96 each
  const int l15 = lane & 15, l4 = lane >> 4;
  const int phys = blockIdx.x;            // grid 512
  const int swz = (phys & 7) * 64 + (phys >> 3);
  const int xcd = swz >> 6, jj = swz & 63;
  const int bm = (xcd >> 1) * 8 + (jj >> 3);   // 0..31
  const int bn = (xcd & 1) * 8 + (jj & 7);     // 0..15

  const ushort* Apan = xs + (size_t)bm * 32 * 4096;
  const ushort* Bpan = wsb + (size_t)bn * 32 * 6144;

  f32x4 acc[4][6];
#pragma unroll
  for (int i = 0; i < 4; i++)
#pragma unroll
    for (int j = 0; j < 6; j++) acc[i][j] = (f32x4)0.f;

#define STAGE_A(buf, kt)                                                        \
  do {                                                                          \
    const ushort* s0 = Apan + (size_t)(kt) * 4096;                              \
    async_copy16(&lA[buf][t * 8], s0 + t * 8);                                  \
    async_copy16(&lA[buf][(t + 256) * 8], s0 + (t + 256) * 8);                  \
  } while (0)
#define STAGE_B(buf, kt)                                                        \
  do {                                                                          \
    const ushort* s2 = Bpan + (size_t)(kt) * 6144;                              \
    async_copy16(&lB[buf][t * 8], s2 + t * 8);                                  \
    async_copy16(&lB[buf][(t + 256) * 8], s2 + (t + 256) * 8);                  \
    async_copy16(&lB[buf][(t + 512) * 8], s2 + (t + 512) * 8);                  \
  } while (0)

  STAGE_A(0, 0);
  STAGE_B(0, 0);
  asm volatile("s_waitcnt vmcnt(0)");
  __builtin_amdgcn_s_barrier();

  for (int kt = 0; kt < 32; ++kt) {
    const int cur = kt & 1;
    s16x8 af[4], bfr[6];
#pragma unroll
    for (int mi = 0; mi < 4; mi++) {
      int ra = wm * 64 + mi * 16 + l15;
      af[mi] = *(const s16x8*)&lA[cur][ra * 32 + ((l4 ^ ((ra >> 1) & 3)) * 8)];
    }
#pragma unroll
    for (int ni = 0; ni < 6; ni++) {
      int rb = wn * 96 + ni * 16 + l15;
      bfr[ni] = *(const s16x8*)&lB[cur][rb * 32 + ((l4 ^ ((rb >> 1) & 3)) * 8)];
    }
    if (kt + 1 < 32) {
      STAGE_A(cur ^ 1, kt + 1);
      STAGE_B(cur ^ 1, kt + 1);
    }
    asm volatile("s_waitcnt lgkmcnt(0)");
    __builtin_amdgcn_sched_barrier(0);
    __builtin_amdgcn_s_setprio(1);
#pragma unroll
    for (int mi = 0; mi < 4; mi++)
#pragma unroll
      for (int ni = 0; ni < 6; ni++)
        acc[mi][ni] = __builtin_amdgcn_mfma_f32_16x16x32_bf16(af[mi], bfr[ni], acc[mi][ni], 0, 0, 0);
    __builtin_amdgcn_s_setprio(0);
    asm volatile("s_waitcnt vmcnt(0)");
    __builtin_amdgcn_s_barrier();
  }
#undef STAGE_A
#undef STAGE_B

#pragma unroll
  for (int ni = 0; ni < 6; ni++) {
    int col = bn * 192 + wn * 96 + ni * 16 + l15;
    int p = col >> 10;
    const float* bias = (p == 0) ? bq : (p == 1) ? bk : bv;
    float b = bias[col & 1023];
    float qscale = (p == 0) ? 0.125f * 1.44269504f : 1.0f;
    int h = (col >> 6) & 15, dd = col & 63;
    size_t base = ((size_t)(p * 16 + h) * 4096) * 64 + dd;
#pragma unroll
    for (int mi = 0; mi < 4; mi++) {
#pragma unroll
      for (int r = 0; r < 4; r++) {
        int s = bm * 128 + wm * 64 + mi * 16 + l4 * 4 + r;
        float v = (acc[mi][ni][r] + b) * qscale;
        qkv[base + (size_t)s * 64] = f2bf(v);
      }
    }
  }
}

// -- banded flash attention v7 (R20 best): split-KV parity, fixed-base softmax --
__global__ __launch_bounds__(512) void attn_local_kernel(
    const ushort* __restrict__ qkv, float* __restrict__ out) {
  __shared__ ushort lds[2][2][2][4096];  // [group][dbuf][0=K,1=V][64x64] = 64KB
  const int bid = blockIdx.x;
  const int wid = (bid & 7) * 64 + (bid >> 3);
  const int hd = wid >> 5;
  const int q0 = (wid & 31) << 7;
  const int t = threadIdx.x;
  const int lane = t & 63, w = t >> 6;
  const int g = w >> 2, wl = w & 3;
  const int tl = t & 255;
  const int l15 = lane & 15, l31 = lane & 31;
  const int b4 = (lane >> 4) & 1, hf = lane >> 5;
  const int qw = q0 + wl * 32;
  const int myq = qw + l31;

  const ushort* __restrict__ Q = qkv;
  const ushort* __restrict__ K = qkv + (size_t)16 * 4096 * 64;
  const ushort* __restrict__ V = K + (size_t)16 * 4096 * 64;

  s16x8 qf[4];
  {
    const ushort* qp = &Q[((size_t)hd * 4096 + myq) * 64];
#pragma unroll
    for (int kc = 0; kc < 4; kc++) qf[kc] = *(const s16x8*)&qp[16 * kc + 8 * hf];
  }

  U8 ones;
  {
    unsigned w1 = (l31 == 0) ? 0x3F803F80u : 0u;
    ones.u[0] = w1; ones.u[1] = w1; ones.u[2] = w1; ones.u[3] = w1;
  }

  f32x16 oa0 = (f32x16)0.f, oa1 = (f32x16)0.f, oden = (f32x16)0.f;

  const unsigned vtr0 = lds_addr(&lds[g][0][1][0]) +
      (unsigned)(hf * 1024 + (l15 >> 2) * 128 + b4 * 32 + (l15 & 3) * 8);

  int kstart = q0 - 256; if (kstart < 0) kstart = 0;
  int kend = q0 + 384; if (kend > 4096) kend = 4096;
  const int R = (kend - kstart) >> 7;

#define STAGE_KV(d, kb)                                                        \
  do {                                                                         \
    const ushort* Kg = &K[((size_t)hd * 4096 + (kb)) * 64];                    \
    const ushort* Vg = &V[((size_t)hd * 4096 + (kb)) * 64];                    \
    _Pragma("unroll") for (int i_ = 0; i_ < 2; i_++) {                         \
      int off = i_ * 2048 + tl * 8;                                            \
      int row = off >> 6;                                                      \
      int c8s = (off >> 3) & 7;                                                \
      async_copy16(&lds[g][d][0][off], &Kg[row * 64 + ((c8s ^ (row & 7)) * 8)]);\
      async_copy16(&lds[g][d][1][off], &Vg[off]);                              \
    }                                                                          \
  } while (0)

  STAGE_KV(0, kstart + g * 64);
  asm volatile("s_waitcnt vmcnt(0)");
  __builtin_amdgcn_s_barrier();

  for (int j = 0; j < R; ++j) {
    const int d = j & 1;
    if (j + 1 < R) STAGE_KV(d ^ 1, kstart + (2 * (j + 1) + g) * 64);
    const int kb = kstart + (2 * j + g) * 64;
    bool active = (kb + 63 >= qw - 256) && (kb <= qw + 31 + 256);
    if (active) {
      const ushort* lK = &lds[g][d][0][0];
      f32x16 st0 = (f32x16)0.f, st1 = (f32x16)0.f;
      __builtin_amdgcn_s_setprio(1);
#pragma unroll
      for (int kc = 0; kc < 4; kc++) {
        int c8 = 2 * kc + hf;
        int r0 = l31;
        s16x8 kf0 = *(const s16x8*)&lK[r0 * 64 + ((c8 ^ (r0 & 7)) * 8)];
        st0 = __builtin_amdgcn_mfma_f32_32x32x16_bf16(kf0, qf[kc], st0, 0, 0, 0);
        int r1 = 32 + l31;
        s16x8 kf1 = *(const s16x8*)&lK[r1 * 64 + ((c8 ^ (r1 & 7)) * 8)];
        st1 = __builtin_amdgcn_mfma_f32_32x32x16_bf16(kf1, qf[kc], st1, 0, 0, 0);
      }
      __builtin_amdgcn_s_setprio(0);
      const bool interior = (kb >= qw - 225) && (kb <= qw + 193);
      if (!interior) {
        int base0 = myq - kb - 4 * hf + 256;
#pragma unroll
        for (int r = 0; r < 16; r++) {
          int ko = (r & 3) + 8 * (r >> 2);
          if (!((unsigned)(base0 - ko) <= 512u)) st0[r] = -3e38f;
          if (!((unsigned)(base0 - 32 - ko) <= 512u)) st1[r] = -3e38f;
        }
      }
      const unsigned vtr = vtr0 + (unsigned)d * 16384u;
      u32x2 v0, v1, v2, v3, v4, v5, v6, v7, v8, v9, v10, v11, v12, v13, v14, v15;
      TRRD(v0, vtr, 0);     TRRD(v1, vtr, 512);  TRRD(v2, vtr, 64);    TRRD(v3, vtr, 576);
      TRRD(v4, vtr, 2048);  TRRD(v5, vtr, 2560); TRRD(v6, vtr, 2112);  TRRD(v7, vtr, 2624);
      TRRD(v8, vtr, 4096);  TRRD(v9, vtr, 4608); TRRD(v10, vtr, 4160); TRRD(v11, vtr, 4672);
      TRRD(v12, vtr, 6144); TRRD(v13, vtr, 6656); TRRD(v14, vtr, 6208); TRRD(v15, vtr, 6720);
      U8 pa0, pa1, pa2, pa3;
#define PACK(STV, RB, OUT)                                                     \
  do {                                                                         \
    float e0 = __builtin_amdgcn_exp2f(STV[RB + 0]);                            \
    float e1 = __builtin_amdgcn_exp2f(STV[RB + 1]);                            \
    float e2 = __builtin_amdgcn_exp2f(STV[RB + 2]);                            \
    float e3 = __builtin_amdgcn_exp2f(STV[RB + 3]);                            \
    float e4 = __builtin_amdgcn_exp2f(STV[RB + 4]);                            \
    float e5 = __builtin_amdgcn_exp2f(STV[RB + 5]);                            \
    float e6 = __builtin_amdgcn_exp2f(STV[RB + 6]);                            \
    float e7 = __builtin_amdgcn_exp2f(STV[RB + 7]);                            \
    unsigned a0, a1, b0, b1;                                                   \
    asm("v_cvt_pk_bf16_f32 %0, %1, %2" : "=v"(a0) : "v"(e0), "v"(e1));         \
    asm("v_cvt_pk_bf16_f32 %0, %1, %2" : "=v"(a1) : "v"(e2), "v"(e3));         \
    asm("v_cvt_pk_bf16_f32 %0, %1, %2" : "=v"(b0) : "v"(e4), "v"(e5));         \
    asm("v_cvt_pk_bf16_f32 %0, %1, %2" : "=v"(b1) : "v"(e6), "v"(e7));         \
    asm volatile("v_permlane32_swap_b32 %0, %1" : "+v"(a0), "+v"(b0));         \
    asm volatile("v_permlane32_swap_b32 %0, %1" : "+v"(a1), "+v"(b1));         \
    OUT.u[0] = a0; OUT.u[1] = a1; OUT.u[2] = b0; OUT.u[3] = b1;                \
  } while (0)
      PACK(st0, 0, pa0); PACK(st0, 8, pa1); PACK(st1, 0, pa2); PACK(st1, 8, pa3);
#undef PACK
#define MFMA3(PA, VA0, VA1, VB0, VB1)                                          \
  do {                                                                         \
    U8 f0, f1;                                                                 \
    f0.u[0] = VA0[0]; f0.u[1] = VA0[1]; f0.u[2] = VA1[0]; f0.u[3] = VA1[1];    \
    f1.u[0] = VB0[0]; f1.u[1] = VB0[1]; f1.u[2] = VB1[0]; f1.u[3] = VB1[1];    \
    __builtin_amdgcn_s_setprio(1);                                             \
    oa0 = __builtin_amdgcn_mfma_f32_32x32x16_bf16(PA.v, f0.v, oa0, 0, 0, 0);   \
    oa1 = __builtin_amdgcn_mfma_f32_32x32x16_bf16(PA.v, f1.v, oa1, 0, 0, 0);   \
    oden = __builtin_amdgcn_mfma_f32_32x32x16_bf16(PA.v, ones.v, oden, 0, 0, 0);\
    __builtin_amdgcn_s_setprio(0);                                             \
  } while (0)
      asm volatile("s_waitcnt lgkmcnt(12)");
      __builtin_amdgcn_sched_barrier(0);
      MFMA3(pa0, v0, v1, v2, v3);
      asm volatile("s_waitcnt lgkmcnt(8)");
      __builtin_amdgcn_sched_barrier(0);
      MFMA3(pa1, v4, v5, v6, v7);
      asm volatile("s_waitcnt lgkmcnt(4)");
      __builtin_amdgcn_sched_barrier(0);
      MFMA3(pa2, v8, v9, v10, v11);
      asm volatile("s_waitcnt lgkmcnt(0)");
      __builtin_amdgcn_sched_barrier(0);
      MFMA3(pa3, v12, v13, v14, v15);
#undef MFMA3
    }
    asm volatile("s_waitcnt vmcnt(0)");
    __builtin_amdgcn_s_barrier();
  }
#undef STAGE_KV

  float* red = (float*)&lds[0][0][0][0];
  if (g == 1) {
    int base = (wl * 64 + lane) * 49;
#pragma unroll
    for (int r = 0; r < 16; r++) {
      red[base + r] = oa0[r];
      red[base + 16 + r] = oa1[r];
      red[base + 32 + r] = oden[r];
    }
  }
  __syncthreads();
  if (g == 0) {
    int base = (wl * 64 + lane) * 49;
#pragma unroll
    for (int r = 0; r < 16; r++) {
      oa0[r] += red[base + r];
      oa1[r] += red[base + 16 + r];
      oden[r] += red[base + 32 + r];
    }
#pragma unroll
    for (int r = 0; r < 16; r++) {
      float den = __shfl(oden[r], lane & 32);
      float linv = 1.0f / den;
      int s = qw + (r & 3) + 8 * (r >> 2) + 4 * hf;
      out[(size_t)s * 1024 + hd * 64 + l31] = oa0[r] * linv;
      out[(size_t)s * 1024 + hd * 64 + 32 + l31] = oa1[r] * linv;
    }
  }
}

extern "C" void kernel_launch(void* const* d_in, const int* in_sizes, int n_in,
                              void* d_out, int out_size, void* d_ws, size_t ws_size,
                              hipStream_t stream) {
  const float* x  = (const float*)d_in[0];
  const float* Wq = (const float*)d_in[1];
  const float* bq = (const float*)d_in[2];
  const float* Wk = (const float*)d_in[3];
  const float* bk = (const float*)d_in[4];
  const float* Wv = (const float*)d_in[5];
  const float* bv = (const float*)d_in[6];

  ushort* qkv = (ushort*)d_ws;                                   // 24 MB
  ushort* xs  = (ushort*)((char*)d_ws + (size_t)25165824);       // 8 MB
  ushort* wsb = xs + (size_t)4096 * 1024;                        // 6 MB
  float* out = (float*)d_out;

  convert_kernel<<<3584, 256, 0, stream>>>(x, Wq, Wk, Wv, xs, wsb);
  qkv_gemm_kernel<<<512, 256, 0, stream>>>(xs, wsb, bq, bk, bv, qkv);
  attn_local_kernel<<<512, 512, 0, stream>>>(qkv, out);
}

// Round 24
// 58.262 us; speedup vs baseline: 2.1351x; 2.1351x over previous
//
#include <hip/hip_runtime.h>
#include <hip/hip_bf16.h>

typedef __attribute__((ext_vector_type(4))) float f32x4;
typedef __attribute__((ext_vector_type(16))) float f32x16;
typedef __attribute__((ext_vector_type(8))) short s16x8;
typedef __attribute__((ext_vector_type(4))) float float4_t;
typedef __attribute__((ext_vector_type(2))) unsigned int u32x2;

union U8 { s16x8 v; unsigned u[4]; };

__device__ __forceinline__ ushort f2bf(float f) {
  union { float f; unsigned u; } v; v.f = f;
  unsigned r = v.u + 0x7fffu + ((v.u >> 16) & 1u);
  return (ushort)(r >> 16);
}

__device__ __forceinline__ void async_copy16(ushort* lds, const ushort* g) {
  __builtin_amdgcn_global_load_lds(
      (const __attribute__((address_space(1))) unsigned int*)g,
      (__attribute__((address_space(3))) unsigned int*)lds, 16, 0, 0);
}

__device__ __forceinline__ unsigned lds_addr(const void* p) {
  return (unsigned)(unsigned long long)(__attribute__((address_space(3))) const void*)p;
}

#define TRRD(dst, addr, off_lit) \
  asm volatile("ds_read_b64_tr_b16 %0, %1 offset:" #off_lit : "=v"(dst) : "v"(addr))

// ---------- merged f32 -> bf16 pre-swizzled panel conversion (BEST, R22) ----------
__global__ __launch_bounds__(256) void convert_kernel(
    const float* __restrict__ x, const float* __restrict__ Wq,
    const float* __restrict__ Wk, const float* __restrict__ Wv,
    ushort* __restrict__ xs, ushort* __restrict__ ws) {
  int b = blockIdx.x;
  if (b < 2048) {
    int c = b * 256 + threadIdx.x;
    int kc = c & 127;
    int m = c >> 7;
    const float4_t* s = (const float4_t*)&x[(size_t)m * 1024 + kc * 8];
    float4_t a0 = s[0], a1 = s[1];
    s16x8 v;
    v[0] = (short)f2bf(a0[0]); v[1] = (short)f2bf(a0[1]);
    v[2] = (short)f2bf(a0[2]); v[3] = (short)f2bf(a0[3]);
    v[4] = (short)f2bf(a1[0]); v[5] = (short)f2bf(a1[1]);
    v[6] = (short)f2bf(a1[2]); v[7] = (short)f2bf(a1[3]);
    int tm = m >> 7, tk = kc >> 3, r = m & 127, c8 = kc & 7;
    *(s16x8*)&xs[((size_t)(tm * 16 + tk) * 128 + r) * 64 + ((c8 ^ (r & 7)) * 8)] = v;
  } else {
    int c = (b - 2048) * 256 + threadIdx.x;
    int kc = c & 127;
    int n = c >> 7;
    int p = n >> 10, nW = n & 1023;
    const float* __restrict__ W = (p == 0) ? Wq : (p == 1) ? Wk : Wv;
    const float4_t* s = (const float4_t*)&W[(size_t)nW * 1024 + kc * 8];
    float4_t a0 = s[0], a1 = s[1];
    s16x8 v;
    v[0] = (short)f2bf(a0[0]); v[1] = (short)f2bf(a0[1]);
    v[2] = (short)f2bf(a0[2]); v[3] = (short)f2bf(a0[3]);
    v[4] = (short)f2bf(a1[0]); v[5] = (short)f2bf(a1[1]);
    v[6] = (short)f2bf(a1[2]); v[7] = (short)f2bf(a1[3]);
    unsigned tn3 = (unsigned)n / 192u;
    unsigned r = (unsigned)n - tn3 * 192u;
    int tk = kc >> 3, c8 = kc & 7;
    *(s16x8*)&ws[((size_t)(tn3 * 16 + tk) * 192 + r) * 64 + ((c8 ^ (r & 7)) * 8)] = v;
  }
}

// -- fused QKV GEMM (BEST, R17/R20/R22): 128x192, BK=64, 4 waves x 64x96, 2 blk/CU --
__global__ __launch_bounds__(256, 2) void qkv_gemm_kernel(
    const ushort* __restrict__ xs, const ushort* __restrict__ wsb,
    const float* __restrict__ bq, const float* __restrict__ bk,
    const float* __restrict__ bv, ushort* __restrict__ qkv) {
  __shared__ ushort lA[2][8192];
  __shared__ ushort lB[2][12288];
  const int t = threadIdx.x;
  const int lane = t & 63, w = t >> 6;
  const int wm = w >> 1, wn = w & 1;
  const int l15 = lane & 15, l4 = lane >> 4;
  const int phys = blockIdx.x;
  const int swz = (phys & 7) * 64 + (phys >> 3);
  const int xcd = swz >> 6, jj = swz & 63;
  const int bm = (xcd >> 1) * 8 + (jj >> 3);
  const int bn = (xcd & 1) * 8 + (jj & 7);

  const ushort* Apan = xs + (size_t)bm * 16 * 8192;
  const ushort* Bpan = wsb + (size_t)bn * 16 * 12288;

  f32x4 acc[4][6];
#pragma unroll
  for (int i = 0; i < 4; i++)
#pragma unroll
    for (int j = 0; j < 6; j++) acc[i][j] = (f32x4)0.f;

#define STAGE_A(buf, kt)                                                        \
  do {                                                                          \
    const ushort* s0 = Apan + (size_t)(kt) * 8192;                              \
    _Pragma("unroll") for (int i_ = 0; i_ < 4; i_++)                            \
      async_copy16(&lA[buf][(t + i_ * 256) * 8], s0 + (t + i_ * 256) * 8);      \
  } while (0)
#define STAGE_B(buf, kt)                                                        \
  do {                                                                          \
    const ushort* s2 = Bpan + (size_t)(kt) * 12288;                             \
    _Pragma("unroll") for (int i_ = 0; i_ < 6; i_++)                            \
      async_copy16(&lB[buf][(t + i_ * 256) * 8], s2 + (t + i_ * 256) * 8);      \
  } while (0)

  STAGE_A(0, 0);
  STAGE_B(0, 0);
  asm volatile("s_waitcnt vmcnt(0)");
  __builtin_amdgcn_s_barrier();

  for (int kt = 0; kt < 16; ++kt) {
    const int cur = kt & 1;
    s16x8 af[4], bfr[6];
#pragma unroll
    for (int mi = 0; mi < 4; mi++) {
      int ra = wm * 64 + mi * 16 + l15;
      int g = l4 ^ (ra & 7);
      af[mi] = *(const s16x8*)&lA[cur][ra * 64 + g * 8];
    }
#pragma unroll
    for (int ni = 0; ni < 6; ni++) {
      int rb = wn * 96 + ni * 16 + l15;
      int g = l4 ^ (rb & 7);
      bfr[ni] = *(const s16x8*)&lB[cur][rb * 64 + g * 8];
    }
    if (kt + 1 < 16) STAGE_A(cur ^ 1, kt + 1);
    asm volatile("s_waitcnt lgkmcnt(0)");
    __builtin_amdgcn_sched_barrier(0);
    __builtin_amdgcn_s_setprio(1);
#pragma unroll
    for (int mi = 0; mi < 4; mi++)
#pragma unroll
      for (int ni = 0; ni < 6; ni++)
        acc[mi][ni] = __builtin_amdgcn_mfma_f32_16x16x32_bf16(af[mi], bfr[ni], acc[mi][ni], 0, 0, 0);
    __builtin_amdgcn_s_setprio(0);
#pragma unroll
    for (int mi = 0; mi < 4; mi++) {
      int ra = wm * 64 + mi * 16 + l15;
      int g = (4 + l4) ^ (ra & 7);
      af[mi] = *(const s16x8*)&lA[cur][ra * 64 + g * 8];
    }
#pragma unroll
    for (int ni = 0; ni < 6; ni++) {
      int rb = wn * 96 + ni * 16 + l15;
      int g = (4 + l4) ^ (rb & 7);
      bfr[ni] = *(const s16x8*)&lB[cur][rb * 64 + g * 8];
    }
    if (kt + 1 < 16) STAGE_B(cur ^ 1, kt + 1);
    asm volatile("s_waitcnt lgkmcnt(0)");
    __builtin_amdgcn_sched_barrier(0);
    __builtin_amdgcn_s_setprio(1);
#pragma unroll
    for (int mi = 0; mi < 4; mi++)
#pragma unroll
      for (int ni = 0; ni < 6; ni++)
        acc[mi][ni] = __builtin_amdgcn_mfma_f32_16x16x32_bf16(af[mi], bfr[ni], acc[mi][ni], 0, 0, 0);
    __builtin_amdgcn_s_setprio(0);
    asm volatile("s_waitcnt vmcnt(0)");
    __builtin_amdgcn_s_barrier();
  }
#undef STAGE_A
#undef STAGE_B

#pragma unroll
  for (int ni = 0; ni < 6; ni++) {
    int col = bn * 192 + wn * 96 + ni * 16 + l15;
    int p = col >> 10;
    const float* bias = (p == 0) ? bq : (p == 1) ? bk : bv;
    float b = bias[col & 1023];
    float qscale = (p == 0) ? 0.125f * 1.44269504f : 1.0f;
    int h = (col >> 6) & 15, dd = col & 63;
    size_t base = ((size_t)(p * 16 + h) * 4096) * 64 + dd;
#pragma unroll
    for (int mi = 0; mi < 4; mi++) {
#pragma unroll
      for (int r = 0; r < 4; r++) {
        int s = bm * 128 + wm * 64 + mi * 16 + l4 * 4 + r;
        float v = (acc[mi][ni][r] + b) * qscale;
        qkv[base + (size_t)s * 64] = f2bf(v);
      }
    }
  }
}

// -- banded flash attention v7 (BEST, R20/R22): split-KV parity, fixed-base softmax --
__global__ __launch_bounds__(512) void attn_local_kernel(
    const ushort* __restrict__ qkv, float* __restrict__ out) {
  __shared__ ushort lds[2][2][2][4096];  // [group][dbuf][0=K,1=V][64x64] = 64KB
  const int bid = blockIdx.x;
  const int wid = (bid & 7) * 64 + (bid >> 3);
  const int hd = wid >> 5;
  const int q0 = (wid & 31) << 7;
  const int t = threadIdx.x;
  const int lane = t & 63, w = t >> 6;
  const int g = w >> 2, wl = w & 3;
  const int tl = t & 255;
  const int l15 = lane & 15, l31 = lane & 31;
  const int b4 = (lane >> 4) & 1, hf = lane >> 5;
  const int qw = q0 + wl * 32;
  const int myq = qw + l31;

  const ushort* __restrict__ Q = qkv;
  const ushort* __restrict__ K = qkv + (size_t)16 * 4096 * 64;
  const ushort* __restrict__ V = K + (size_t)16 * 4096 * 64;

  s16x8 qf[4];
  {
    const ushort* qp = &Q[((size_t)hd * 4096 + myq) * 64];
#pragma unroll
    for (int kc = 0; kc < 4; kc++) qf[kc] = *(const s16x8*)&qp[16 * kc + 8 * hf];
  }

  U8 ones;
  {
    unsigned w1 = (l31 == 0) ? 0x3F803F80u : 0u;
    ones.u[0] = w1; ones.u[1] = w1; ones.u[2] = w1; ones.u[3] = w1;
  }

  f32x16 oa0 = (f32x16)0.f, oa1 = (f32x16)0.f, oden = (f32x16)0.f;

  const unsigned vtr0 = lds_addr(&lds[g][0][1][0]) +
      (unsigned)(hf * 1024 + (l15 >> 2) * 128 + b4 * 32 + (l15 & 3) * 8);

  int kstart = q0 - 256; if (kstart < 0) kstart = 0;
  int kend = q0 + 384; if (kend > 4096) kend = 4096;
  const int R = (kend - kstart) >> 7;

#define STAGE_KV(d, kb)                                                        \
  do {                                                                         \
    const ushort* Kg = &K[((size_t)hd * 4096 + (kb)) * 64];                    \
    const ushort* Vg = &V[((size_t)hd * 4096 + (kb)) * 64];                    \
    _Pragma("unroll") for (int i_ = 0; i_ < 2; i_++) {                         \
      int off = i_ * 2048 + tl * 8;                                            \
      int row = off >> 6;                                                      \
      int c8s = (off >> 3) & 7;                                                \
      async_copy16(&lds[g][d][0][off], &Kg[row * 64 + ((c8s ^ (row & 7)) * 8)]);\
      async_copy16(&lds[g][d][1][off], &Vg[off]);                              \
    }                                                                          \
  } while (0)

  STAGE_KV(0, kstart + g * 64);
  asm volatile("s_waitcnt vmcnt(0)");
  __builtin_amdgcn_s_barrier();

  for (int j = 0; j < R; ++j) {
    const int d = j & 1;
    if (j + 1 < R) STAGE_KV(d ^ 1, kstart + (2 * (j + 1) + g) * 64);
    const int kb = kstart + (2 * j + g) * 64;
    bool active = (kb + 63 >= qw - 256) && (kb <= qw + 31 + 256);
    if (active) {
      const ushort* lK = &lds[g][d][0][0];
      f32x16 st0 = (f32x16)0.f, st1 = (f32x16)0.f;
      __builtin_amdgcn_s_setprio(1);
#pragma unroll
      for (int kc = 0; kc < 4; kc++) {
        int c8 = 2 * kc + hf;
        int r0 = l31;
        s16x8 kf0 = *(const s16x8*)&lK[r0 * 64 + ((c8 ^ (r0 & 7)) * 8)];
        st0 = __builtin_amdgcn_mfma_f32_32x32x16_bf16(kf0, qf[kc], st0, 0, 0, 0);
        int r1 = 32 + l31;
        s16x8 kf1 = *(const s16x8*)&lK[r1 * 64 + ((c8 ^ (r1 & 7)) * 8)];
        st1 = __builtin_amdgcn_mfma_f32_32x32x16_bf16(kf1, qf[kc], st1, 0, 0, 0);
      }
      __builtin_amdgcn_s_setprio(0);
      const bool interior = (kb >= qw - 225) && (kb <= qw + 193);
      if (!interior) {
        int base0 = myq - kb - 4 * hf + 256;
#pragma unroll
        for (int r = 0; r < 16; r++) {
          int ko = (r & 3) + 8 * (r >> 2);
          if (!((unsigned)(base0 - ko) <= 512u)) st0[r] = -3e38f;
          if (!((unsigned)(base0 - 32 - ko) <= 512u)) st1[r] = -3e38f;
        }
      }
      const unsigned vtr = vtr0 + (unsigned)d * 16384u;
      u32x2 v0, v1, v2, v3, v4, v5, v6, v7, v8, v9, v10, v11, v12, v13, v14, v15;
      TRRD(v0, vtr, 0);     TRRD(v1, vtr, 512);  TRRD(v2, vtr, 64);    TRRD(v3, vtr, 576);
      TRRD(v4, vtr, 2048);  TRRD(v5, vtr, 2560); TRRD(v6, vtr, 2112);  TRRD(v7, vtr, 2624);
      TRRD(v8, vtr, 4096);  TRRD(v9, vtr, 4608); TRRD(v10, vtr, 4160); TRRD(v11, vtr, 4672);
      TRRD(v12, vtr, 6144); TRRD(v13, vtr, 6656); TRRD(v14, vtr, 6208); TRRD(v15, vtr, 6720);
      U8 pa0, pa1, pa2, pa3;
#define PACK(STV, RB, OUT)                                                     \
  do {                                                                         \
    float e0 = __builtin_amdgcn_exp2f(STV[RB + 0]);                            \
    float e1 = __builtin_amdgcn_exp2f(STV[RB + 1]);                            \
    float e2 = __builtin_amdgcn_exp2f(STV[RB + 2]);                            \
    float e3 = __builtin_amdgcn_exp2f(STV[RB + 3]);                            \
    float e4 = __builtin_amdgcn_exp2f(STV[RB + 4]);                            \
    float e5 = __builtin_amdgcn_exp2f(STV[RB + 5]);                            \
    float e6 = __builtin_amdgcn_exp2f(STV[RB + 6]);                            \
    float e7 = __builtin_amdgcn_exp2f(STV[RB + 7]);                            \
    unsigned a0, a1, b0, b1;                                                   \
    asm("v_cvt_pk_bf16_f32 %0, %1, %2" : "=v"(a0) : "v"(e0), "v"(e1));         \
    asm("v_cvt_pk_bf16_f32 %0, %1, %2" : "=v"(a1) : "v"(e2), "v"(e3));         \
    asm("v_cvt_pk_bf16_f32 %0, %1, %2" : "=v"(b0) : "v"(e4), "v"(e5));         \
    asm("v_cvt_pk_bf16_f32 %0, %1, %2" : "=v"(b1) : "v"(e6), "v"(e7));         \
    asm volatile("v_permlane32_swap_b32 %0, %1" : "+v"(a0), "+v"(b0));         \
    asm volatile("v_permlane32_swap_b32 %0, %1" : "+v"(a1), "+v"(b1));         \
    OUT.u[0] = a0; OUT.u[1] = a1; OUT.u[2] = b0; OUT.u[3] = b1;                \
  } while (0)
      PACK(st0, 0, pa0); PACK(st0, 8, pa1); PACK(st1, 0, pa2); PACK(st1, 8, pa3);
#undef PACK
#define MFMA3(PA, VA0, VA1, VB0, VB1)                                          \
  do {                                                                         \
    U8 f0, f1;                                                                 \
    f0.u[0] = VA0[0]; f0.u[1] = VA0[1]; f0.u[2] = VA1[0]; f0.u[3] = VA1[1];    \
    f1.u[0] = VB0[0]; f1.u[1] = VB0[1]; f1.u[2] = VB1[0]; f1.u[3] = VB1[1];    \
    __builtin_amdgcn_s_setprio(1);                                             \
    oa0 = __builtin_amdgcn_mfma_f32_32x32x16_bf16(PA.v, f0.v, oa0, 0, 0, 0);   \
    oa1 = __builtin_amdgcn_mfma_f32_32x32x16_bf16(PA.v, f1.v, oa1, 0, 0, 0);   \
    oden = __builtin_amdgcn_mfma_f32_32x32x16_bf16(PA.v, ones.v, oden, 0, 0, 0);\
    __builtin_amdgcn_s_setprio(0);                                             \
  } while (0)
      asm volatile("s_waitcnt lgkmcnt(12)");
      __builtin_amdgcn_sched_barrier(0);
      MFMA3(pa0, v0, v1, v2, v3);
      asm volatile("s_waitcnt lgkmcnt(8)");
      __builtin_amdgcn_sched_barrier(0);
      MFMA3(pa1, v4, v5, v6, v7);
      asm volatile("s_waitcnt lgkmcnt(4)");
      __builtin_amdgcn_sched_barrier(0);
      MFMA3(pa2, v8, v9, v10, v11);
      asm volatile("s_waitcnt lgkmcnt(0)");
      __builtin_amdgcn_sched_barrier(0);
      MFMA3(pa3, v12, v13, v14, v15);
#undef MFMA3
    }
    asm volatile("s_waitcnt vmcnt(0)");
    __builtin_amdgcn_s_barrier();
  }
#undef STAGE_KV

  float* red = (float*)&lds[0][0][0][0];
  if (g == 1) {
    int base = (wl * 64 + lane) * 49;
#pragma unroll
    for (int r = 0; r < 16; r++) {
      red[base + r] = oa0[r];
      red[base + 16 + r] = oa1[r];
      red[base + 32 + r] = oden[r];
    }
  }
  __syncthreads();
  if (g == 0) {
    int base = (wl * 64 + lane) * 49;
#pragma unroll
    for (int r = 0; r < 16; r++) {
      oa0[r] += red[base + r];
      oa1[r] += red[base + 16 + r];
      oden[r] += red[base + 32 + r];
    }
#pragma unroll
    for (int r = 0; r < 16; r++) {
      float den = __shfl(oden[r], lane & 32);
      float linv = 1.0f / den;
      int s = qw + (r & 3) + 8 * (r >> 2) + 4 * hf;
      out[(size_t)s * 1024 + hd * 64 + l31] = oa0[r] * linv;
      out[(size_t)s * 1024 + hd * 64 + 32 + l31] = oa1[r] * linv;
    }
  }
}

extern "C" void kernel_launch(void* const* d_in, const int* in_sizes, int n_in,
                              void* d_out, int out_size, void* d_ws, size_t ws_size,
                              hipStream_t stream) {
  const float* x  = (const float*)d_in[0];
  const float* Wq = (const float*)d_in[1];
  const float* bq = (const float*)d_in[2];
  const float* Wk = (const float*)d_in[3];
  const float* bk = (const float*)d_in[4];
  const float* Wv = (const float*)d_in[5];
  const float* bv = (const float*)d_in[6];

  ushort* qkv = (ushort*)d_ws;                                   // 24 MB
  ushort* xs  = (ushort*)((char*)d_ws + (size_t)25165824);       // 8 MB
  ushort* wsb = xs + (size_t)4096 * 1024;                        // 6 MB
  float* out = (float*)d_out;

  convert_kernel<<<3584, 256, 0, stream>>>(x, Wq, Wk, Wv, xs, wsb);
  qkv_gemm_kernel<<<512, 256, 0, stream>>>(xs, wsb, bq, bk, bv, qkv);
  attn_local_kernel<<<512, 512, 0, stream>>>(qkv, out);
}